// Round 3
// baseline (1468.744 us; speedup 1.0000x reference)
//
#include <hip/hip_runtime.h>

#define PTS 8192          // B*N = 4*2048 points
#define HDIM 512
#define BN_EPS 1e-4f

typedef unsigned short u16;
typedef u16 u16x8 __attribute__((ext_vector_type(8)));
typedef short s16x8 __attribute__((ext_vector_type(8)));
typedef float f32x4 __attribute__((ext_vector_type(4)));

__device__ __forceinline__ float bf2f(u16 u) {
  unsigned x = ((unsigned)u) << 16;
  return __builtin_bit_cast(float, x);
}
__device__ __forceinline__ u16 f2bf(float f) {
  unsigned x = __builtin_bit_cast(unsigned, f);
  x += 0x7fffu + ((x >> 16) & 1u);
  return (u16)(x >> 16);
}
__device__ __forceinline__ float sigf(float x) {
  return __builtin_amdgcn_rcpf(1.f + __expf(-x));
}
__device__ __forceinline__ float fast_tanh(float x) {
  float e = __expf(2.f * x);
  return 1.f - 2.f * __builtin_amdgcn_rcpf(e + 1.f);
}
__device__ __forceinline__ void gl2lds16(const u16* g, u16* l) {
  __builtin_amdgcn_global_load_lds(
      (const __attribute__((address_space(1))) void*)g,
      (__attribute__((address_space(3))) void*)l, 16, 0, 0);
}

// ---------------------------------------------------------------- prep
struct PrepArgs {
  const float *W1, *W2;
  u16 *W1b, *W2b;
  const float* c;
  u16* cb;
  const float *Wg0, *Wg1, *Wg2, *Wb0, *Wb1, *Wb2;
  const float *bg0, *bg1, *bg2;
  u16* Wpack;          // [6*512][64] bf16 (Wg0,Wg1,Wg2,Wb0,Wb1,Wb2; cols 1..64)
  float* bias_pack;    // [3072]
  const float *x, *m1, *v1, *lg1, *be1;
  float *x_cur, *lp_state;
  const float *Wg3, *bg3, *Wb3;
  float *G3, *B3;
};
__global__ void prep_kernel(PrepArgs a) {
  int i = blockIdx.x * 256 + threadIdx.x;   // 0 .. 524287
  if (i < 512 * 512) { a.W1b[i] = f2bf(a.W1[i]); a.W2b[i] = f2bf(a.W2[i]); }
  if (i < PTS * 64) a.cb[i] = f2bf(a.c[i]);
  if (i < 6 * 512 * 64) {
    int sec = i >> 15;
    int within = i & 32767;
    int o = within >> 6, k = within & 63;
    const float* src[6] = {a.Wg0, a.Wg1, a.Wg2, a.Wb0, a.Wb1, a.Wb2};
    a.Wpack[i] = f2bf(src[sec][o * 65 + 1 + k]);
  }
  if (i < 3072) {
    int sec = i >> 9, o = i & 511;
    const float* bgl[3] = {a.bg0, a.bg1, a.bg2};
    a.bias_pack[i] = (sec < 3) ? bgl[sec][o] : 0.f;
  }
  if (i < PTS * 3) {
    int d = i % 3;
    a.x_cur[i] = (a.x[i] - a.m1[d]) * __expf(a.lg1[d]) * rsqrtf(a.v1[d] + BN_EPS) + a.be1[d];
  }
  if (i < PTS) a.lp_state[i] = 0.f;
  // gates for layer3: wave per point
  {
    int lane = threadIdx.x & 63;
    int p = (blockIdx.x * 256 + threadIdx.x) >> 6;   // 0..8191
    float cv = a.c[(size_t)p * 64 + lane];
    float ag[3], ab[3];
    #pragma unroll
    for (int o = 0; o < 3; ++o) {
      ag[o] = cv * a.Wg3[o * 65 + 1 + lane];
      ab[o] = cv * a.Wb3[o * 65 + 1 + lane];
    }
    #pragma unroll
    for (int off = 32; off > 0; off >>= 1) {
      #pragma unroll
      for (int o = 0; o < 3; ++o) {
        ag[o] += __shfl_xor(ag[o], off);
        ab[o] += __shfl_xor(ab[o], off);
      }
    }
    if (lane == 0) {
      #pragma unroll
      for (int o = 0; o < 3; ++o) {
        a.G3[p * 3 + o] = ag[o] + a.bg3[o];
        a.B3[p * 3 + o] = ab[o];
      }
    }
  }
}

// ---------------------------------------------------------------- gates GEMM
struct GatesGemmArgs {
  const u16 *A, *W;        // cb [8192][64], Wpack [3072][64]
  const float* bias;       // [3072]
  u16* GB;                 // [6][8192][512]
};
__global__ __launch_bounds__(256) void gates_gemm(GatesGemmArgs a) {
  __shared__ u16 As[128 * 32];
  __shared__ u16 Bs[128 * 32];
  int tid = threadIdx.x;
  int m0 = blockIdx.x * 128, n0 = blockIdx.y * 128;
  int wave = tid >> 6, lane = tid & 63;
  int wm = (wave & 1) * 64, wn = (wave >> 1) * 64;
  int lr = lane & 15, quad = lane >> 4;

  int rowS = tid >> 2, colS = (tid & 3) * 8;
  const u16* gA0 = a.A + (size_t)(m0 + rowS) * 64 + colS;
  const u16* gB0 = a.W + (size_t)(n0 + rowS) * 64 + colS;
  u16* sA0 = &As[tid * 8];
  u16* sA1 = &As[2048 + tid * 8];
  u16* sB0 = &Bs[tid * 8];
  u16* sB1 = &Bs[2048 + tid * 8];

  f32x4 acc[4][4];
  #pragma unroll
  for (int i = 0; i < 4; ++i)
    #pragma unroll
    for (int j = 0; j < 4; ++j)
      #pragma unroll
      for (int r = 0; r < 4; ++r) acc[i][j][r] = 0.f;

  for (int k0 = 0; k0 < 64; k0 += 32) {
    if (k0) __syncthreads();
    gl2lds16(gA0 + k0, sA0);
    gl2lds16(gA0 + (size_t)64 * 64 + k0, sA1);
    gl2lds16(gB0 + k0, sB0);
    gl2lds16(gB0 + (size_t)64 * 64 + k0, sB1);
    __syncthreads();
    s16x8 af[4], bfr[4];
    #pragma unroll
    for (int i = 0; i < 4; ++i)
      af[i] = *(const s16x8*)&As[(wm + i * 16 + lr) * 32 + quad * 8];
    #pragma unroll
    for (int j = 0; j < 4; ++j)
      bfr[j] = *(const s16x8*)&Bs[(wn + j * 16 + lr) * 32 + quad * 8];
    #pragma unroll
    for (int i = 0; i < 4; ++i)
      #pragma unroll
      for (int j = 0; j < 4; ++j)
        acc[i][j] = __builtin_amdgcn_mfma_f32_16x16x32_bf16(af[i], bfr[j], acc[i][j], 0, 0, 0);
  }

  #pragma unroll
  for (int j = 0; j < 4; ++j) {
    int n = n0 + wn + j * 16 + lr;
    int sec = n >> 9, col = n & 511;
    float bv = a.bias[n];
    u16* outp = a.GB + (size_t)sec * PTS * 512 + col;
    #pragma unroll
    for (int i = 0; i < 4; ++i) {
      int mrow = m0 + wm + i * 16 + quad * 4;
      #pragma unroll
      for (int r = 0; r < 4; ++r)
        outp[(size_t)(mrow + r) * 512] = f2bf(acc[i][j][r] + bv);
    }
  }
}

// ---------------------------------------------------------------- stage_front
// RK4 fold of previous stage's accum + layer0 for current stage. Wave per point.
struct SFArgs {
  const float* sqrtT;
  float ts_prev, ts_cur;
  int mode_prev;             // -1 none, 0,1,2 stage folds, 3 step-end fold
  float* accum;              // [PTS][64]
  const float *G3, *B3, *Wg3, *Wb3, *b3;
  float *x_cur, *kx, *kl, *lp_state;
  const float *W0, *b0, *Wg0, *Wb0;
  const u16 *G0, *Bc0;
  u16* H1;
};
__global__ void stage_front(SFArgs a) {
  int tid = threadIdx.x, wave = tid >> 6, lane = tid & 63;
  int p = blockIdx.x * 4 + wave;
  float s0 = a.sqrtT[0];
  float dt = s0 * s0 * (1.f / 3.f);

  float xe0, xe1, xe2;
  if (a.mode_prev < 0) {
    a.accum[(size_t)p * 64 + lane] = 0.f;
    xe0 = a.x_cur[p * 3]; xe1 = a.x_cur[p * 3 + 1]; xe2 = a.x_cur[p * 3 + 2];
  } else {
    float v = a.accum[(size_t)p * 64 + lane];
    a.accum[(size_t)p * 64 + lane] = 0.f;
    v += __shfl_xor(v, 8);
    v += __shfl_xor(v, 16);
    v += __shfl_xor(v, 32);
    float fr[3] = {__shfl(v, 0), __shfl(v, 1), __shfl(v, 2)};
    float dj[3] = {__shfl(v, 3), __shfl(v, 4), __shfl(v, 5)};
    float tp = a.ts_prev * dt;
    float dx[3], gate[3];
    #pragma unroll
    for (int r = 0; r < 3; ++r) {
      gate[r] = sigf(a.G3[p * 3 + r] + tp * a.Wg3[r * 65]);
      float bias = a.B3[p * 3 + r] + tp * a.Wb3[r * 65];
      dx[r] = fmaf(fr[r] + a.b3[r], gate[r], bias);
    }
    float klv = -(dj[0] * gate[0] + dj[1] * gate[1] + dj[2] * gate[2]);
    float xc[3] = {a.x_cur[p * 3], a.x_cur[p * 3 + 1], a.x_cur[p * 3 + 2]};
    int m = a.mode_prev;
    if (m == 0) {
      xe0 = xc[0] + 0.5f * dt * dx[0];
      xe1 = xc[1] + 0.5f * dt * dx[1];
      xe2 = xc[2] + 0.5f * dt * dx[2];
      if (lane == 0) {
        #pragma unroll
        for (int r = 0; r < 3; ++r) a.kx[p * 3 + r] = dx[r];
        a.kl[p] = klv;
      }
    } else if (m == 1) {
      xe0 = xc[0] + 0.5f * dt * dx[0];
      xe1 = xc[1] + 0.5f * dt * dx[1];
      xe2 = xc[2] + 0.5f * dt * dx[2];
      if (lane == 0) {
        #pragma unroll
        for (int r = 0; r < 3; ++r) a.kx[p * 3 + r] += 2.f * dx[r];
        a.kl[p] += 2.f * klv;
      }
    } else if (m == 2) {
      xe0 = xc[0] + dt * dx[0];
      xe1 = xc[1] + dt * dx[1];
      xe2 = xc[2] + dt * dx[2];
      if (lane == 0) {
        #pragma unroll
        for (int r = 0; r < 3; ++r) a.kx[p * 3 + r] += 2.f * dx[r];
        a.kl[p] += 2.f * klv;
      }
    } else {
      float sc = dt * (1.f / 6.f);
      xe0 = xc[0] + sc * (a.kx[p * 3] + dx[0]);
      xe1 = xc[1] + sc * (a.kx[p * 3 + 1] + dx[1]);
      xe2 = xc[2] + sc * (a.kx[p * 3 + 2] + dx[2]);
      if (lane == 0) {
        a.x_cur[p * 3] = xe0; a.x_cur[p * 3 + 1] = xe1; a.x_cur[p * 3 + 2] = xe2;
        a.lp_state[p] += sc * (a.kl[p] + klv);
      }
    }
  }

  // layer0 at ts_cur
  float t = a.ts_cur * dt;
  int o0 = lane * 8;
  u16x8 g8 = *(const u16x8*)(a.G0 + (size_t)p * 512 + o0);
  u16x8 c8 = *(const u16x8*)(a.Bc0 + (size_t)p * 512 + o0);
  u16x8 oh, od0, od1, od2;
  #pragma unroll
  for (int jj = 0; jj < 8; ++jj) {
    int o = o0 + jj;
    float w0 = a.W0[o * 3], w1 = a.W0[o * 3 + 1], w2 = a.W0[o * 3 + 2];
    float u = fmaf(w0, xe0, fmaf(w1, xe1, w2 * xe2)) + a.b0[o];
    float gate = sigf(bf2f(g8[jj]) + t * a.Wg0[o * 65]);
    float bias = bf2f(c8[jj]) + t * a.Wb0[o * 65];
    float z = fmaf(u, gate, bias);
    float h = fast_tanh(z);
    float wm = (1.f - h * h) * gate;
    oh[jj] = f2bf(h);
    od0[jj] = f2bf(wm * w0);
    od1[jj] = f2bf(wm * w1);
    od2[jj] = f2bf(wm * w2);
  }
  size_t base = (size_t)(p * 4) * 512 + o0;
  *(u16x8*)(a.H1 + base) = oh;
  *(u16x8*)(a.H1 + base + 512) = od0;
  *(u16x8*)(a.H1 + base + 1024) = od1;
  *(u16x8*)(a.H1 + base + 1536) = od2;
}

// ---------------------------------------------------------------- middle GEMM
// C[m][n] = sum_k A[m][k]*W[n][k]; m = 4*p + stream; BK=64 as two BK=32 sub-tiles.
// FUSE==0: gate/tanh epilogue -> Out streams. FUSE==1: + layer3 partial dots -> accum.
struct GemmArgs {
  const u16 *A, *W;
  const float *bvec, *Wg, *Wbm, *sqrtT;
  const u16 *G, *Bc;
  u16* Out;
  const float* W3;     // [3][512]
  float* accum;        // [PTS][64]
  float ts;
};
template <int FUSE>
__global__ __launch_bounds__(256) void gemm_mid(GemmArgs a) {
  __shared__ u16 As[128 * 64];
  __shared__ u16 Bs[128 * 64];
  int tid = threadIdx.x;
  int m0 = blockIdx.x * 128, n0 = blockIdx.y * 128;
  int wave = tid >> 6, lane = tid & 63;
  int wm = (wave & 1) * 64, wn = (wave >> 1) * 64;
  int lr = lane & 15, quad = lane >> 4;

  int rowS = tid >> 2, colS = (tid & 3) * 8;
  const u16* gA = a.A + (size_t)(m0 + rowS) * 512 + colS;
  const u16* gB = a.W + (size_t)(n0 + rowS) * 512 + colS;
  u16* sA0 = &As[tid * 8];
  u16* sB0 = &Bs[tid * 8];

  f32x4 acc[4][4];
  #pragma unroll
  for (int i = 0; i < 4; ++i)
    #pragma unroll
    for (int j = 0; j < 4; ++j)
      #pragma unroll
      for (int r = 0; r < 4; ++r) acc[i][j][r] = 0.f;

  for (int k0 = 0; k0 < 512; k0 += 64) {
    if (k0) __syncthreads();
    gl2lds16(gA + k0, sA0);
    gl2lds16(gA + (size_t)64 * 512 + k0, sA0 + 2048);
    gl2lds16(gA + k0 + 32, sA0 + 4096);
    gl2lds16(gA + (size_t)64 * 512 + k0 + 32, sA0 + 6144);
    gl2lds16(gB + k0, sB0);
    gl2lds16(gB + (size_t)64 * 512 + k0, sB0 + 2048);
    gl2lds16(gB + k0 + 32, sB0 + 4096);
    gl2lds16(gB + (size_t)64 * 512 + k0 + 32, sB0 + 6144);
    __syncthreads();
    #pragma unroll
    for (int h = 0; h < 2; ++h) {
      s16x8 af[4], bfr[4];
      #pragma unroll
      for (int i = 0; i < 4; ++i)
        af[i] = *(const s16x8*)&As[h * 4096 + (wm + i * 16 + lr) * 32 + quad * 8];
      #pragma unroll
      for (int j = 0; j < 4; ++j)
        bfr[j] = *(const s16x8*)&Bs[h * 4096 + (wn + j * 16 + lr) * 32 + quad * 8];
      #pragma unroll
      for (int i = 0; i < 4; ++i)
        #pragma unroll
        for (int j = 0; j < 4; ++j)
          acc[i][j] = __builtin_amdgcn_mfma_f32_16x16x32_bf16(af[i], bfr[j], acc[i][j], 0, 0, 0);
    }
  }

  float s0 = a.sqrtT[0];
  float dt = s0 * s0 * (1.f / 3.f);
  float t = a.ts * dt;

  float a6[4][6];
  if (FUSE) {
    #pragma unroll
    for (int i = 0; i < 4; ++i)
      #pragma unroll
      for (int r = 0; r < 6; ++r) a6[i][r] = 0.f;
  }

  #pragma unroll
  for (int j = 0; j < 4; ++j) {
    int n = n0 + wn + j * 16 + lr;
    float bvn = a.bvec[n];
    float wg0 = a.Wg[n * 65], wb0 = a.Wbm[n * 65];
    float w30, w31, w32;
    if (FUSE) { w30 = a.W3[n]; w31 = a.W3[512 + n]; w32 = a.W3[1024 + n]; }
    #pragma unroll
    for (int i = 0; i < 4; ++i) {
      int mrow = m0 + wm + i * 16 + quad * 4;     // = 4*p
      int p = mrow >> 2;
      float gate = sigf(bf2f(a.G[(size_t)p * 512 + n]) + t * wg0);
      float bias = bf2f(a.Bc[(size_t)p * 512 + n]) + t * wb0;
      f32x4 u = acc[i][j];
      float z = fmaf(u[0] + bvn, gate, bias);
      float h = fast_tanh(z);
      float wmf = (1.f - h * h) * gate;
      if (FUSE) {
        a6[i][0] = fmaf(h, w30, a6[i][0]);
        a6[i][1] = fmaf(h, w31, a6[i][1]);
        a6[i][2] = fmaf(h, w32, a6[i][2]);
        a6[i][3] = fmaf(u[1] * wmf, w30, a6[i][3]);
        a6[i][4] = fmaf(u[2] * wmf, w31, a6[i][4]);
        a6[i][5] = fmaf(u[3] * wmf, w32, a6[i][5]);
      } else {
        size_t ob = (size_t)mrow * 512 + n;
        a.Out[ob]        = f2bf(h);
        a.Out[ob + 512]  = f2bf(u[1] * wmf);
        a.Out[ob + 1024] = f2bf(u[2] * wmf);
        a.Out[ob + 1536] = f2bf(u[3] * wmf);
      }
    }
  }

  if (FUSE) {
    int slot = blockIdx.y * 2 + (wave >> 1);
    #pragma unroll
    for (int i = 0; i < 4; ++i) {
      float v0 = a6[i][0], v1 = a6[i][1], v2 = a6[i][2];
      float v3 = a6[i][3], v4 = a6[i][4], v5 = a6[i][5];
      #pragma unroll
      for (int mask = 1; mask <= 8; mask <<= 1) {
        v0 += __shfl_xor(v0, mask);
        v1 += __shfl_xor(v1, mask);
        v2 += __shfl_xor(v2, mask);
        v3 += __shfl_xor(v3, mask);
        v4 += __shfl_xor(v4, mask);
        v5 += __shfl_xor(v5, mask);
      }
      int p = (m0 >> 2) + (wm >> 2) + i * 4 + quad;
      float val = (lr == 0) ? v0 : (lr == 1) ? v1 : (lr == 2) ? v2
                : (lr == 3) ? v3 : (lr == 4) ? v4 : v5;
      if (lr < 6) a.accum[(size_t)p * 64 + slot * 8 + lr] = val;
    }
  }
}

// ---------------------------------------------------------------- finalize
// mode-3 fold for the last stage + BN2 + write outputs; wave per point.
struct FinArgs {
  const float* sqrtT;
  float ts_prev;
  const float* accum;
  const float *G3, *B3, *Wg3, *Wb3, *b3;
  const float *x_cur, *kx, *kl;
  float* lp_state;
  const float *m2, *v2, *lg2, *be2;
  float* out_x;
};
__global__ void finalize_kernel(FinArgs a) {
  int tid = threadIdx.x, wave = tid >> 6, lane = tid & 63;
  int p = blockIdx.x * 4 + wave;
  float s0 = a.sqrtT[0];
  float dt = s0 * s0 * (1.f / 3.f);

  float v = a.accum[(size_t)p * 64 + lane];
  v += __shfl_xor(v, 8);
  v += __shfl_xor(v, 16);
  v += __shfl_xor(v, 32);
  float fr[3] = {__shfl(v, 0), __shfl(v, 1), __shfl(v, 2)};
  float dj[3] = {__shfl(v, 3), __shfl(v, 4), __shfl(v, 5)};
  if (lane == 0) {
    float tp = a.ts_prev * dt;
    float dx[3], gate[3];
    #pragma unroll
    for (int r = 0; r < 3; ++r) {
      gate[r] = sigf(a.G3[p * 3 + r] + tp * a.Wg3[r * 65]);
      float bias = a.B3[p * 3 + r] + tp * a.Wb3[r * 65];
      dx[r] = fmaf(fr[r] + a.b3[r], gate[r], bias);
    }
    float klv = -(dj[0] * gate[0] + dj[1] * gate[1] + dj[2] * gate[2]);
    float sc = dt * (1.f / 6.f);
    #pragma unroll
    for (int r = 0; r < 3; ++r) {
      float xf = a.x_cur[p * 3 + r] + sc * (a.kx[p * 3 + r] + dx[r]);
      a.out_x[p * 3 + r] = (xf - a.m2[r]) * __expf(a.lg2[r]) * rsqrtf(a.v2[r] + BN_EPS) + a.be2[r];
    }
    a.lp_state[p] += sc * (a.kl[p] + klv);
  }
}

__global__ void finish_lp(const float* __restrict__ lp_state,
                          const float* __restrict__ v1, const float* __restrict__ lg1,
                          const float* __restrict__ v2, const float* __restrict__ lg2,
                          float* __restrict__ out) {
  int b = blockIdx.x, tid = threadIdx.x;
  float s = 0.f;
  for (int n = tid; n < 2048; n += 256) s += lp_state[b * 2048 + n];
  __shared__ float red[256];
  red[tid] = s;
  __syncthreads();
  for (int w = 128; w > 0; w >>= 1) {
    if (tid < w) red[tid] += red[tid + w];
    __syncthreads();
  }
  if (tid == 0) {
    float ld = 0.f;
    for (int d = 0; d < 3; ++d) {
      ld += lg1[d] - 0.5f * logf(v1[d] + BN_EPS);
      ld += lg2[d] - 0.5f * logf(v2[d] + BN_EPS);
    }
    out[b] = red[0] - 2048.f * ld;
  }
}

// ---------------------------------------------------------------- launch
extern "C" void kernel_launch(void* const* d_in, const int* in_sizes, int n_in,
                              void* d_out, int out_size, void* d_ws, size_t ws_size,
                              hipStream_t stream) {
  const float* x        = (const float*)d_in[0];
  const float* c        = (const float*)d_in[1];
  const float* bn1_mean = (const float*)d_in[2];
  const float* bn1_var  = (const float*)d_in[3];
  const float* bn1_lg   = (const float*)d_in[4];
  const float* bn1_beta = (const float*)d_in[5];
  const float* bn2_mean = (const float*)d_in[6];
  const float* bn2_var  = (const float*)d_in[7];
  const float* bn2_lg   = (const float*)d_in[8];
  const float* bn2_beta = (const float*)d_in[9];
  const float* sqrtT    = (const float*)d_in[10];
  const float* W0  = (const float*)d_in[11];
  const float* b0  = (const float*)d_in[12];
  const float* Wg0 = (const float*)d_in[13];
  const float* bg0 = (const float*)d_in[14];
  const float* Wb0 = (const float*)d_in[15];
  const float* W1  = (const float*)d_in[16];
  const float* b1  = (const float*)d_in[17];
  const float* Wg1 = (const float*)d_in[18];
  const float* bg1 = (const float*)d_in[19];
  const float* Wb1 = (const float*)d_in[20];
  const float* W2  = (const float*)d_in[21];
  const float* b2  = (const float*)d_in[22];
  const float* Wg2 = (const float*)d_in[23];
  const float* bg2 = (const float*)d_in[24];
  const float* Wb2 = (const float*)d_in[25];
  const float* W3  = (const float*)d_in[26];
  const float* b3  = (const float*)d_in[27];
  const float* Wg3 = (const float*)d_in[28];
  const float* bg3 = (const float*)d_in[29];
  const float* Wb3 = (const float*)d_in[30];

  char* base = (char*)d_ws;
  size_t off = 0;
  auto alloc = [&](size_t bytes) -> void* {
    void* pp = base + off;
    off += (bytes + 255) & ~(size_t)255;
    return pp;
  };
  u16* W1b = (u16*)alloc((size_t)512 * 512 * 2);
  u16* W2b = (u16*)alloc((size_t)512 * 512 * 2);
  u16* cb  = (u16*)alloc((size_t)PTS * 64 * 2);
  u16* Wpack = (u16*)alloc((size_t)6 * 512 * 64 * 2);
  float* bias_pack = (float*)alloc((size_t)3072 * 4);
  u16* GB = (u16*)alloc((size_t)6 * PTS * 512 * 2);
  const size_t SZ = (size_t)PTS * 512;
  u16* G[3]  = {GB, GB + SZ, GB + 2 * SZ};
  u16* Bc[3] = {GB + 3 * SZ, GB + 4 * SZ, GB + 5 * SZ};
  float* G3f = (float*)alloc((size_t)PTS * 3 * 4);
  float* B3f = (float*)alloc((size_t)PTS * 3 * 4);
  u16* HA = (u16*)alloc((size_t)4 * PTS * 512 * 2);
  u16* HB = (u16*)alloc((size_t)4 * PTS * 512 * 2);
  float* accum    = (float*)alloc((size_t)PTS * 64 * 4);
  float* x_cur    = (float*)alloc((size_t)PTS * 3 * 4);
  float* kx       = (float*)alloc((size_t)PTS * 3 * 4);
  float* kl       = (float*)alloc((size_t)PTS * 4);
  float* lp_state = (float*)alloc((size_t)PTS * 4);
  (void)ws_size; (void)in_sizes; (void)n_in; (void)out_size;

  PrepArgs pa{W1, W2, W1b, W2b, c, cb, Wg0, Wg1, Wg2, Wb0, Wb1, Wb2,
              bg0, bg1, bg2, Wpack, bias_pack, x, bn1_mean, bn1_var,
              bn1_lg, bn1_beta, x_cur, lp_state, Wg3, bg3, Wb3, G3f, B3f};
  prep_kernel<<<2048, 256, 0, stream>>>(pa);

  GatesGemmArgs gg{cb, Wpack, bias_pack, GB};
  gates_gemm<<<dim3(64, 24), 256, 0, stream>>>(gg);

  auto ts_of = [](int s) -> float {
    static const float frac[4] = {0.f, 0.5f, 0.5f, 1.f};
    return (float)(s >> 2) + frac[s & 3];
  };

  for (int s = 0; s < 12; ++s) {
    float ts = ts_of(s);
    int mode_prev = (s == 0) ? -1 : ((s - 1) & 3);
    float ts_prev = (s == 0) ? 0.f : ts_of(s - 1);

    SFArgs sf{sqrtT, ts_prev, ts, mode_prev, accum, G3f, B3f, Wg3, Wb3, b3,
              x_cur, kx, kl, lp_state, W0, b0, Wg0, Wb0, G[0], Bc[0], HA};
    stage_front<<<PTS / 4, 256, 0, stream>>>(sf);

    GemmArgs g1{HA, W1b, b1, Wg1, Wb1, sqrtT, G[1], Bc[1], HB, nullptr, nullptr, ts};
    gemm_mid<0><<<dim3(256, 4), 256, 0, stream>>>(g1);

    GemmArgs g2{HB, W2b, b2, Wg2, Wb2, sqrtT, G[2], Bc[2], nullptr, W3, accum, ts};
    gemm_mid<1><<<dim3(256, 4), 256, 0, stream>>>(g2);
  }

  FinArgs fa{sqrtT, 3.f, accum, G3f, B3f, Wg3, Wb3, b3, x_cur, kx, kl,
             lp_state, bn2_mean, bn2_var, bn2_lg, bn2_beta, (float*)d_out};
  finalize_kernel<<<PTS / 4, 256, 0, stream>>>(fa);
  finish_lp<<<4, 256, 0, stream>>>(lp_state, bn1_var, bn1_lg, bn2_var, bn2_lg,
                                   (float*)d_out + PTS * 3);
}